// Round 4
// baseline (10326.038 us; speedup 1.0000x reference)
//
#include <hip/hip_runtime.h>
#include <stdint.h>

#define F_DIM 512
#define CAP   64
#define MAXV  9216

typedef unsigned long long u64;

// ---------------- per-vertex squared norm (fp64 accumulate) ----------------
__global__ void k_sq(const float* __restrict__ img, double* __restrict__ sqd, int V) {
  int v = blockIdx.x;
  if (v >= V) return;
  const float* row = img + (size_t)v * F_DIM;
  double s = 0.0;
  for (int f = threadIdx.x; f < F_DIM; f += 64) {
    double x = (double)row[f];
    s += x * x;
  }
  for (int off = 32; off > 0; off >>= 1) s += __shfl_down(s, off);
  if (threadIdx.x == 0) sqd[v] = s;
}

// ---------------- zero degrees + edge eligibility (boundary test) ----------
__global__ void k_prep(const float* __restrict__ vs, const int* __restrict__ edges,
                       int V, int E, int* __restrict__ deg, unsigned char* __restrict__ elig) {
  int i = blockIdx.x * blockDim.x + threadIdx.x;
  if (i < V) deg[i] = 0;
  if (i < E) {
    int a = edges[i], b = edges[E + i];
    float ax = vs[2 * a], ay = vs[2 * a + 1];
    float bx = vs[2 * b], by = vs[2 * b + 1];
    const float eps = 1e-3f;
    const float hi = 1.0f - 1e-3f;
    bool ba = (ax < eps) || (ax > hi) || (ay < eps) || (ay > hi);
    bool bb = (bx < eps) || (bx > hi) || (by < eps) || (by > hi);
    elig[i] = (!ba && !bb) ? 1 : 0;
  }
}

// ---------------- build neighbor lists -------------------------------------
__global__ void k_lists(const int* __restrict__ edges, int E,
                        int* __restrict__ deg, unsigned short* __restrict__ nbr) {
  int e = blockIdx.x * blockDim.x + threadIdx.x;
  if (e >= E) return;
  int a = edges[e], b = edges[E + e];
  int ia = atomicAdd(&deg[a], 1);
  nbr[a * CAP + ia] = (unsigned short)b;
  int ib = atomicAdd(&deg[b], 1);
  nbr[b * CAP + ib] = (unsigned short)a;
}

// ---------------- sortable keys: prio(double) top bits | edge id -----------
__global__ void k_keys(const double* __restrict__ sqd, const int* __restrict__ edges,
                       int E, int P, u64* __restrict__ keys) {
  int e = blockIdx.x * blockDim.x + threadIdx.x;
  if (e >= P) return;
  if (e < E) {
    double prio = sqd[edges[e]] + sqd[edges[E + e]];
    u64 bits = (u64)__double_as_longlong(prio);  // prio > 0 -> bits monotone
    keys[e] = (bits & ~0xFFFFull) | (u64)e;
  } else {
    keys[e] = ~0ull;
  }
}

// ---------------- single-block bitonic sort, LDS-staged --------------------
#define SCH 4096
__global__ void __launch_bounds__(1024)
k_sort(u64* __restrict__ keys, int n) {
  __shared__ u64 buf[SCH];
  int tid = threadIdx.x;
  int nt = blockDim.x;
  int ch = n < SCH ? n : SCH;
  // phase A: full bitonic of each chunk (k = 2..ch), direction by global idx
  for (int chunk = 0; chunk < n; chunk += ch) {
    for (int i = tid; i < ch; i += nt) buf[i] = keys[chunk + i];
    __syncthreads();
    for (int k = 2; k <= ch; k <<= 1) {
      for (int j = k >> 1; j > 0; j >>= 1) {
        for (int li = tid; li < ch; li += nt) {
          int lj = li ^ j;
          if (lj > li) {
            u64 x = buf[li], y = buf[lj];
            bool up = (((chunk + li) & k) == 0);
            if (up ? (x > y) : (x < y)) { buf[li] = y; buf[lj] = x; }
          }
        }
        __syncthreads();
      }
    }
    for (int i = tid; i < ch; i += nt) keys[chunk + i] = buf[i];
    __syncthreads();
  }
  // phase B: k = 2*ch..n; global steps for j>=ch, LDS sweep for j<ch
  for (int k = (ch << 1); k <= n; k <<= 1) {
    for (int j = k >> 1; j >= ch; j >>= 1) {
      for (int i = tid; i < n; i += nt) {
        int ixj = i ^ j;
        if (ixj > i) {
          u64 x = keys[i], y = keys[ixj];
          bool up = ((i & k) == 0);
          if (up ? (x > y) : (x < y)) { keys[i] = y; keys[ixj] = x; }
        }
      }
      __syncthreads();
    }
    for (int chunk = 0; chunk < n; chunk += ch) {
      for (int i = tid; i < ch; i += nt) buf[i] = keys[chunk + i];
      __syncthreads();
      for (int j = ch >> 1; j > 0; j >>= 1) {
        for (int li = tid; li < ch; li += nt) {
          int lj = li ^ j;
          if (lj > li) {
            u64 x = buf[li], y = buf[lj];
            bool up = (((chunk + li) & k) == 0);
            if (up ? (x > y) : (x < y)) { buf[li] = y; buf[lj] = x; }
          }
        }
        __syncthreads();
      }
      for (int i = tid; i < ch; i += nt) keys[chunk + i] = buf[i];
      __syncthreads();
    }
  }
}

// ---------------- gather sorted (v0,v1,elig) into one packed word ----------
__global__ void k_reorder(const u64* __restrict__ keys, const int* __restrict__ edges,
                          const unsigned char* __restrict__ elig, int E,
                          unsigned* __restrict__ packed) {
  int t = blockIdx.x * blockDim.x + threadIdx.x;
  if (t >= E) return;
  int eid = (int)(keys[t] & 0xFFFFull);
  unsigned v0 = (unsigned)edges[eid];
  unsigned v1 = (unsigned)edges[E + eid];
  unsigned el = (unsigned)elig[eid];
  packed[t] = v0 | (v1 << 14) | (el << 28);
}

// swizzled LDS row layout: entry i of candidate c
__device__ __forceinline__ int swz(int i, int c) {
  return (i << 6) + (c ^ ((i << 1) & 62));
}

__device__ __forceinline__ u64 readlane64(u64 m, int idx) {
  unsigned lo = __builtin_amdgcn_readlane((unsigned)m, idx);
  unsigned hi = __builtin_amdgcn_readlane((unsigned)(m >> 32), idx);
  return ((u64)hi << 32) | lo;
}

// ---------------- sequential greedy decimation (single wave) ---------------
__global__ void __launch_bounds__(64)
k_decimate(int E, int V, int target, const unsigned* __restrict__ packed,
           const int* __restrict__ deg_g, unsigned short* __restrict__ nbr,
           int2* __restrict__ events, int* __restrict__ nev_out) {
  __shared__ unsigned short degs[MAXV];
  __shared__ unsigned short touch[MAXV];
  __shared__ unsigned short rowA[64 * 64];
  __shared__ unsigned short rowB[64 * 64];
  int lane = threadIdx.x;
  if (V > MAXV) return;
  for (int v = lane; v < V; v += 64) { degs[v] = (unsigned short)deg_g[v]; touch[v] = 0; }
  __syncthreads();

  int count = V, nev = 0;
  unsigned ctag = 0;
  bool stop = false;
  u64 lanebit = 1ull << lane;
  u64 below = lanebit - 1;

  // copy own candidate's two rows (d0/d1 entries) into swizzled LDS columns
  auto copy_rows = [&](bool active, int w0, int w1, int dd0, int dd1) {
    uint4 a[8], b[8];
    const uint4* pa = (const uint4*)(nbr + w0 * CAP);
    const uint4* pb = (const uint4*)(nbr + w1 * CAP);
#pragma unroll
    for (int c = 0; c < 8; ++c) {
      if (active && c * 8 < dd0) a[c] = pa[c];
      if (active && c * 8 < dd1) b[c] = pb[c];
    }
#pragma unroll
    for (int c = 0; c < 8; ++c) {
      if (__ballot(active && c * 8 < dd0)) {
        unsigned w;
        w = a[c].x; if (active && c*8+0 < dd0) rowA[swz(c*8+0, lane)] = (unsigned short)(w & 0xFFFF);
                    if (active && c*8+1 < dd0) rowA[swz(c*8+1, lane)] = (unsigned short)(w >> 16);
        w = a[c].y; if (active && c*8+2 < dd0) rowA[swz(c*8+2, lane)] = (unsigned short)(w & 0xFFFF);
                    if (active && c*8+3 < dd0) rowA[swz(c*8+3, lane)] = (unsigned short)(w >> 16);
        w = a[c].z; if (active && c*8+4 < dd0) rowA[swz(c*8+4, lane)] = (unsigned short)(w & 0xFFFF);
                    if (active && c*8+5 < dd0) rowA[swz(c*8+5, lane)] = (unsigned short)(w >> 16);
        w = a[c].w; if (active && c*8+6 < dd0) rowA[swz(c*8+6, lane)] = (unsigned short)(w & 0xFFFF);
                    if (active && c*8+7 < dd0) rowA[swz(c*8+7, lane)] = (unsigned short)(w >> 16);
      }
      if (__ballot(active && c * 8 < dd1)) {
        unsigned w;
        w = b[c].x; if (active && c*8+0 < dd1) rowB[swz(c*8+0, lane)] = (unsigned short)(w & 0xFFFF);
                    if (active && c*8+1 < dd1) rowB[swz(c*8+1, lane)] = (unsigned short)(w >> 16);
        w = b[c].y; if (active && c*8+2 < dd1) rowB[swz(c*8+2, lane)] = (unsigned short)(w & 0xFFFF);
                    if (active && c*8+3 < dd1) rowB[swz(c*8+3, lane)] = (unsigned short)(w >> 16);
        w = b[c].z; if (active && c*8+4 < dd1) rowB[swz(c*8+4, lane)] = (unsigned short)(w & 0xFFFF);
                    if (active && c*8+5 < dd1) rowB[swz(c*8+5, lane)] = (unsigned short)(w >> 16);
        w = b[c].w; if (active && c*8+6 < dd1) rowB[swz(c*8+6, lane)] = (unsigned short)(w & 0xFFFF);
                    if (active && c*8+7 < dd1) rowB[swz(c*8+7, lane)] = (unsigned short)(w >> 16);
      }
    }
    asm volatile("s_waitcnt lgkmcnt(0)" ::: "memory");
    __builtin_amdgcn_sched_barrier(0);
  };

  // per-lane exact intersection -> membership masks
  auto eval = [&](bool active, int dd0, int dd1, u64& mA, u64& mB) {
    mA = 0; mB = 0;
    int e0 = active ? dd0 : 0;
    int e1 = active ? dd1 : 0;
    for (int i = 0; i < e0; ++i) {
      unsigned ai = rowA[swz(i, lane)];
      bool hit = false;
      for (int j = 0; j < e1; ++j) {
        unsigned bj = rowB[swz(j, lane)];
        bool m = (ai == bj);
        hit = hit || m;
        if (m) mB |= 1ull << j;
      }
      if (hit) mA |= 1ull << i;
    }
  };

  for (int base = 0; base < E && !stop; base += 64) {
    int t = base + lane;
    unsigned pk = (t < E) ? packed[t] : 0u;
    int mv0 = (int)(pk & 0x3FFFu);
    int mv1 = (int)((pk >> 14) & 0x3FFFu);
    // prior merges' stores must be visible to this batch's row loads
    asm volatile("s_waitcnt vmcnt(0) lgkmcnt(0)" ::: "memory");
    __builtin_amdgcn_sched_barrier(0);
    int d0 = degs[mv0], d1 = degs[mv1];
    bool cand = (t < E) && ((pk >> 28) & 1u) && d0 > 0 && d1 > 0;

    copy_rows(cand, mv0, mv1, d0, d1);
    u64 mA, mB;
    eval(cand, d0, d1, mA, mB);

    u64 pend = __ballot(cand);
    u64 acc  = __ballot(cand && __popcll(mA) == 2);

    while (acc) {
      int idx = __builtin_ctzll(acc);
      acc &= acc - 1;
      pend &= ~((2ull << idx) - 1);   // only candidates after idx still pending

      unsigned pkc = __builtin_amdgcn_readlane(pk, idx);
      int cv0 = (int)(pkc & 0x3FFFu);
      int cv1 = (int)((pkc >> 14) & 0x3FFFu);
      int D0 = __builtin_amdgcn_readlane(d0, idx);
      int D1 = __builtin_amdgcn_readlane(d1, idx);
      u64 mAi = readlane64(mA, idx);
      u64 mBi = readlane64(mB, idx);

      unsigned aa = (unsigned)rowA[swz(lane, idx)];
      unsigned bb = (unsigned)rowB[swz(lane, idx)];
      bool v_a = lane < D0;
      bool v_b = lane < D1;
      bool bInA = ((mBi >> lane) & 1) != 0;

      u64 keepMask = __ballot(v_a && aa != (unsigned)cv1);
      u64 addMask  = __ballot(v_b && bb != (unsigned)cv0 && !bInA);
      int nKeep = __popcll(keepMask);
      int newd  = nKeep + __popcll(addMask);
      if (newd > CAP) newd = CAP;
      if (keepMask & lanebit) {
        nbr[cv0 * CAP + __popcll(keepMask & below)] = (unsigned short)aa;
      }
      if (addMask & lanebit) {
        int pos = nKeep + __popcll(addMask & below);
        if (pos < CAP) nbr[cv0 * CAP + pos] = (unsigned short)bb;
      }

      // update each u in N(v1)\{v0}: replace v1 by v0, or drop v1 if v0 present
      bool doU = v_b && (bb != (unsigned)cv0);
      if (doU) {
        int u = (int)bb;
        int du = degs[u];
        const uint4* rowp = (const uint4*)(nbr + u * CAP);
        unsigned tg = (unsigned)cv1;
        int posv1 = -1;
        int nw = (du + 7) >> 3;
        for (int c = 0; c < nw; ++c) {
          uint4 w = rowp[c];
          int b8 = c << 3;
          if ((w.x & 0xFFFFu) == tg && b8 + 0 < du) posv1 = b8 + 0;
          if ((w.x >> 16)     == tg && b8 + 1 < du) posv1 = b8 + 1;
          if ((w.y & 0xFFFFu) == tg && b8 + 2 < du) posv1 = b8 + 2;
          if ((w.y >> 16)     == tg && b8 + 3 < du) posv1 = b8 + 3;
          if ((w.z & 0xFFFFu) == tg && b8 + 4 < du) posv1 = b8 + 4;
          if ((w.z >> 16)     == tg && b8 + 5 < du) posv1 = b8 + 5;
          if ((w.w & 0xFFFFu) == tg && b8 + 6 < du) posv1 = b8 + 6;
          if ((w.w >> 16)     == tg && b8 + 7 < du) posv1 = b8 + 7;
        }
        if (posv1 >= 0) {
          if (bInA) {
            nbr[u * CAP + posv1] = nbr[u * CAP + du - 1];
            degs[u] = (unsigned short)(du - 1);
          } else {
            nbr[u * CAP + posv1] = (unsigned short)cv0;
          }
        }
      }

      ctag++;
      if (v_b) touch[bb] = (unsigned short)ctag;       // N(cv1), incl. cv0
      if (lane == 0) {
        touch[cv1] = (unsigned short)ctag;
        degs[cv0] = (unsigned short)newd;
        degs[cv1] = 0;
        events[nev] = make_int2(cv0, cv1);
      }
      nev++;
      count--;
      if (count <= target) { stop = true; break; }

      if (acc | pend) {
        // drain stores + LDS before staleness checks / re-eval loads
        asm volatile("s_waitcnt vmcnt(0) lgkmcnt(0)" ::: "memory");
        __builtin_amdgcn_sched_barrier(0);
        bool amPend = (pend & lanebit) != 0;
        bool aff = amPend && (touch[mv0] == (unsigned short)ctag ||
                              touch[mv1] == (unsigned short)ctag);
        u64 affm = __ballot(aff);
        if (affm) {
          int nd0 = aff ? degs[mv0] : d0;
          int nd1 = aff ? degs[mv1] : d1;
          bool nc = aff && nd0 > 0 && nd1 > 0;
          copy_rows(nc, mv0, mv1, nd0, nd1);
          u64 nmA, nmB;
          eval(nc, nd0, nd1, nmA, nmB);
          if (aff) { d0 = nd0; d1 = nd1; mA = nmA; mB = nmB; }
          u64 alivem = __ballot(!aff || nc);
          u64 naccm  = __ballot(aff && nc && __popcll(nmA) == 2);
          acc  = ((acc & ~affm) | (naccm & pend)) & alivem;
          pend = pend & alivem;
        }
      }
    }
  }
  if (lane == 0) nev_out[0] = nev;
}

// ---------------- reverse-replay: owner + weight per original vertex -------
__global__ void __launch_bounds__(256)
k_weights(const int2* __restrict__ events, const int* __restrict__ nev_p,
          int V, int* __restrict__ own, float* __restrict__ wgt) {
  __shared__ int O[MAXV];
  __shared__ unsigned short H[MAXV];
  __shared__ int2 evb[256];
  int tid = threadIdx.x;
  if (V > MAXV) return;
  for (int v = tid; v < V; v += blockDim.x) { O[v] = v; H[v] = 0; }
  int n = nev_p[0];
  __syncthreads();
  int nb = (n + 255) >> 8;
  for (int b = nb - 1; b >= 0; --b) {
    int bbase = b << 8;
    int cnt = n - bbase; if (cnt > 256) cnt = 256;
    if (tid < cnt) evb[tid] = events[bbase + tid];
    __syncthreads();
    if (tid == 0) {
      for (int k = cnt - 1; k >= 0; --k) {
        int2 ev = evb[k];
        int h = (int)H[ev.x] + 1;
        H[ev.x] = (unsigned short)h;
        H[ev.y] = (unsigned short)h;
        O[ev.y] = O[ev.x];
      }
    }
    __syncthreads();
  }
  for (int v = tid; v < V; v += blockDim.x) {
    own[v] = O[v];
    wgt[v] = ldexpf(1.0f, -(int)H[v]);
  }
}

// ---------------- output ---------------------------------------------------
__global__ void k_zero(float4* __restrict__ out, int n4) {
  int i = blockIdx.x * blockDim.x + threadIdx.x;
  if (i < n4) out[i] = make_float4(0.f, 0.f, 0.f, 0.f);
}

__global__ void k_scatter(const float* __restrict__ img, const int* __restrict__ own,
                          const float* __restrict__ wgt, float* __restrict__ out, int V) {
  int v = blockIdx.x;
  if (v >= V) return;
  float w = wgt[v];
  int o = own[v];
  const float* src = img + (size_t)v * F_DIM;
  float* dst = out + (size_t)o * F_DIM;
  if (w == 1.0f) {
    for (int f = threadIdx.x; f < F_DIM; f += blockDim.x) dst[f] = src[f];
  } else {
    for (int f = threadIdx.x; f < F_DIM; f += blockDim.x) atomicAdd(&dst[f], w * src[f]);
  }
}

extern "C" void kernel_launch(void* const* d_in, const int* in_sizes, int n_in,
                              void* d_out, int out_size, void* d_ws, size_t ws_size,
                              hipStream_t stream) {
  const float* img  = (const float*)d_in[0];
  const int* edges  = (const int*)d_in[1];
  const float* vs   = (const float*)d_in[2];
  int V = in_sizes[2] / 2;
  int E = in_sizes[1] / 2;
  int P = 1; while (P < E) P <<= 1;

  char* wsp = (char*)d_ws;
  size_t off = 0;
  auto alloc = [&](size_t bytes) -> void* {
    void* p = (void*)(wsp + off);
    off = (off + bytes + 255) & ~(size_t)255;
    return p;
  };
  double* sqd          = (double*)alloc((size_t)V * 8);
  u64* keys            = (u64*)alloc((size_t)P * 8);
  int* deg             = (int*)alloc((size_t)V * 4);
  unsigned short* nbr  = (unsigned short*)alloc((size_t)V * CAP * 2);
  unsigned char* elig  = (unsigned char*)alloc((size_t)E);
  unsigned* packed     = (unsigned*)alloc((size_t)E * 4);
  int2* events         = (int2*)alloc((size_t)(V / 2 + 64) * 8);
  int* nev             = (int*)alloc(256);
  int* own             = (int*)alloc((size_t)V * 4);
  float* wgt           = (float*)alloc((size_t)V * 4);

  hipLaunchKernelGGL(k_sq, dim3(V), dim3(64), 0, stream, img, sqd, V);
  int mx = V > E ? V : E;
  hipLaunchKernelGGL(k_prep, dim3((mx + 255) / 256), dim3(256), 0, stream, vs, edges, V, E, deg, elig);
  hipLaunchKernelGGL(k_lists, dim3((E + 255) / 256), dim3(256), 0, stream, edges, E, deg, nbr);
  hipLaunchKernelGGL(k_keys, dim3((P + 255) / 256), dim3(256), 0, stream, sqd, edges, E, P, keys);
  hipLaunchKernelGGL(k_sort, dim3(1), dim3(1024), 0, stream, keys, P);
  hipLaunchKernelGGL(k_reorder, dim3((E + 255) / 256), dim3(256), 0, stream, keys, edges, elig, E, packed);
  hipLaunchKernelGGL(k_decimate, dim3(1), dim3(64), 0, stream,
                     E, V, V / 2, packed, deg, nbr, events, nev);
  hipLaunchKernelGGL(k_weights, dim3(1), dim3(256), 0, stream, events, nev, V, own, wgt);
  int n4 = (V * F_DIM) / 4;
  hipLaunchKernelGGL(k_zero, dim3((n4 + 255) / 256), dim3(256), 0, stream, (float4*)d_out, n4);
  hipLaunchKernelGGL(k_scatter, dim3(V), dim3(256), 0, stream, img, own, wgt, (float*)d_out, V);
}

// Round 5
// 5607.012 us; speedup vs baseline: 1.8416x; 1.8416x over previous
//
#include <hip/hip_runtime.h>
#include <stdint.h>

#define F_DIM 512
#define CAP   64
#define MAXV  9216
#define GD    8

typedef unsigned long long u64;

// ---------------- per-vertex squared norm (fp64 accumulate) ----------------
__global__ void k_sq(const float* __restrict__ img, double* __restrict__ sqd, int V) {
  int v = blockIdx.x;
  if (v >= V) return;
  const float* row = img + (size_t)v * F_DIM;
  double s = 0.0;
  for (int f = threadIdx.x; f < F_DIM; f += 64) {
    double x = (double)row[f];
    s += x * x;
  }
  for (int off = 32; off > 0; off >>= 1) s += __shfl_down(s, off);
  if (threadIdx.x == 0) sqd[v] = s;
}

// ---------------- zero degrees + edge eligibility (boundary test) ----------
__global__ void k_prep(const float* __restrict__ vs, const int* __restrict__ edges,
                       int V, int E, int* __restrict__ deg, unsigned char* __restrict__ elig) {
  int i = blockIdx.x * blockDim.x + threadIdx.x;
  if (i < V) deg[i] = 0;
  if (i < E) {
    int a = edges[i], b = edges[E + i];
    float ax = vs[2 * a], ay = vs[2 * a + 1];
    float bx = vs[2 * b], by = vs[2 * b + 1];
    const float eps = 1e-3f;
    const float hi = 1.0f - 1e-3f;
    bool ba = (ax < eps) || (ax > hi) || (ay < eps) || (ay > hi);
    bool bb = (bx < eps) || (bx > hi) || (by < eps) || (by > hi);
    elig[i] = (!ba && !bb) ? 1 : 0;
  }
}

// ---------------- build neighbor lists -------------------------------------
__global__ void k_lists(const int* __restrict__ edges, int E,
                        int* __restrict__ deg, unsigned short* __restrict__ nbr) {
  int e = blockIdx.x * blockDim.x + threadIdx.x;
  if (e >= E) return;
  int a = edges[e], b = edges[E + e];
  int ia = atomicAdd(&deg[a], 1);
  nbr[a * CAP + ia] = (unsigned short)b;
  int ib = atomicAdd(&deg[b], 1);
  nbr[b * CAP + ib] = (unsigned short)a;
}

// ---------------- sortable keys: prio(double) top bits | edge id -----------
__global__ void k_keys(const double* __restrict__ sqd, const int* __restrict__ edges,
                       int E, int P, u64* __restrict__ keys) {
  int e = blockIdx.x * blockDim.x + threadIdx.x;
  if (e >= P) return;
  if (e < E) {
    double prio = sqd[edges[e]] + sqd[edges[E + e]];
    u64 bits = (u64)__double_as_longlong(prio);  // prio > 0 -> bits monotone
    keys[e] = (bits & ~0xFFFFull) | (u64)e;
  } else {
    keys[e] = ~0ull;
  }
}

// ---------------- single-block bitonic sort, LDS-staged --------------------
#define SCH 4096
__global__ void __launch_bounds__(1024)
k_sort(u64* __restrict__ keys, int n) {
  __shared__ u64 buf[SCH];
  int tid = threadIdx.x;
  int nt = blockDim.x;
  int ch = n < SCH ? n : SCH;
  for (int chunk = 0; chunk < n; chunk += ch) {
    for (int i = tid; i < ch; i += nt) buf[i] = keys[chunk + i];
    __syncthreads();
    for (int k = 2; k <= ch; k <<= 1) {
      for (int j = k >> 1; j > 0; j >>= 1) {
        for (int li = tid; li < ch; li += nt) {
          int lj = li ^ j;
          if (lj > li) {
            u64 x = buf[li], y = buf[lj];
            bool up = (((chunk + li) & k) == 0);
            if (up ? (x > y) : (x < y)) { buf[li] = y; buf[lj] = x; }
          }
        }
        __syncthreads();
      }
    }
    for (int i = tid; i < ch; i += nt) keys[chunk + i] = buf[i];
    __syncthreads();
  }
  for (int k = (ch << 1); k <= n; k <<= 1) {
    for (int j = k >> 1; j >= ch; j >>= 1) {
      for (int i = tid; i < n; i += nt) {
        int ixj = i ^ j;
        if (ixj > i) {
          u64 x = keys[i], y = keys[ixj];
          bool up = ((i & k) == 0);
          if (up ? (x > y) : (x < y)) { keys[i] = y; keys[ixj] = x; }
        }
      }
      __syncthreads();
    }
    for (int chunk = 0; chunk < n; chunk += ch) {
      for (int i = tid; i < ch; i += nt) buf[i] = keys[chunk + i];
      __syncthreads();
      for (int j = ch >> 1; j > 0; j >>= 1) {
        for (int li = tid; li < ch; li += nt) {
          int lj = li ^ j;
          if (lj > li) {
            u64 x = buf[li], y = buf[lj];
            bool up = (((chunk + li) & k) == 0);
            if (up ? (x > y) : (x < y)) { buf[li] = y; buf[lj] = x; }
          }
        }
        __syncthreads();
      }
      for (int i = tid; i < ch; i += nt) keys[chunk + i] = buf[i];
      __syncthreads();
    }
  }
}

// ---------------- gather sorted (v0,v1,elig) into one packed word ----------
__global__ void k_reorder(const u64* __restrict__ keys, const int* __restrict__ edges,
                          const unsigned char* __restrict__ elig, int E,
                          unsigned* __restrict__ packed) {
  int t = blockIdx.x * blockDim.x + threadIdx.x;
  if (t >= E) return;
  int eid = (int)(keys[t] & 0xFFFFull);
  unsigned v0 = (unsigned)edges[eid];
  unsigned v1 = (unsigned)edges[E + eid];
  unsigned el = (unsigned)elig[eid];
  packed[t] = v0 | (v1 << 14) | (el << 28);
}

// path-halving find on LDS union-find
__device__ __forceinline__ int findroot(unsigned short* ren, int x) {
  while (true) {
    int p = ren[x];
    if (p == x) return x;
    int q = ren[p];
    if (q == p) return p;
    ren[x] = (unsigned short)q;   // halving (benign race; roots invariant)
    x = q;
  }
}

// ---------------- sequential greedy decimation (single wave) ---------------
// Lazy-merge design: rows are raw (may contain stale ids / duplicates);
// ren[] union-find resolves to live roots at read time; rln[] is exact raw
// length. Merge = append raw(v1) to raw(v0) + ren[v1]=v0 (no neighbor scans).
__global__ void __launch_bounds__(64)
k_decimate(int E, int V, int target, const unsigned* __restrict__ packed,
           const int* __restrict__ deg_g, unsigned short* __restrict__ nbr,
           int2* __restrict__ events, int* __restrict__ nev_out) {
  __shared__ unsigned short ren[MAXV];
  __shared__ unsigned short rln[MAXV];
  __shared__ unsigned markA[MAXV];
  __shared__ unsigned markB[MAXV];
  const int lane = threadIdx.x;
  if (V > MAXV) return;
  for (int v = lane; v < V; v += 64) {
    ren[v] = (unsigned short)v;
    rln[v] = (unsigned short)deg_g[v];
    markA[v] = 0u;
    markB[v] = 0u;
  }
  __syncthreads();

  int count = V, nev = 0;
  unsigned ctr = 0;
  bool stop = false;
  const u64 lanebit = 1ull << lane;
  const u64 below = lanebit - 1;

  for (int base = 0; base < E && !stop; base += 64) {
    int t = base + lane;
    unsigned pk = (t < E) ? packed[t] : 0u;
    int mv0 = (int)(pk & 0x3FFFu);
    int mv1 = (int)((pk >> 14) & 0x3FFFu);
    bool cand = (t < E) && ((pk >> 28) & 1u) &&
                (ren[mv0] == (unsigned short)mv0) &&
                (ren[mv1] == (unsigned short)mv1);
    u64 cm = __ballot(cand);

    while (cm != 0 && !stop) {
      // ---- pick up to GD candidates (static indices only) ----
      int ids[GD];
#pragma unroll
      for (int g = 0; g < GD; ++g) {
        if (cm) { ids[g] = __builtin_ctzll(cm); cm &= cm - 1; }
        else ids[g] = -1;
      }
      // drain prior appends, then gather all group rows (coalesced 128B each)
      asm volatile("s_waitcnt vmcnt(0)" ::: "memory");
      __builtin_amdgcn_sched_barrier(0);
      int gcv0[GD], gcv1[GD];
      unsigned ga[GD], gb[GD];
#pragma unroll
      for (int g = 0; g < GD; ++g) {
        if (ids[g] >= 0) {
          unsigned pkc = __builtin_amdgcn_readlane(pk, ids[g]);
          gcv0[g] = (int)(pkc & 0x3FFFu);
          gcv1[g] = (int)((pkc >> 14) & 0x3FFFu);
          ga[g] = (unsigned)nbr[gcv0[g] * CAP + lane];
          gb[g] = (unsigned)nbr[gcv1[g] * CAP + lane];
        } else { gcv0[g] = -1; gcv1[g] = -1; ga[g] = 0; gb[g] = 0; }
      }
      int app[GD];
#pragma unroll
      for (int g = 0; g < GD; ++g) app[g] = -1;

#pragma unroll
      for (int g = 0; g < GD; ++g) {
        if (ids[g] < 0 || stop) continue;
        int cv0 = gcv0[g], cv1 = gcv1[g];
        // aliveness (current LDS state)
        if (ren[cv0] != (unsigned short)cv0 || ren[cv1] != (unsigned short)cv1) continue;
        // staleness: only in-group accepted commits modify rows (row of app[j])
        bool stale = false;
#pragma unroll
        for (int j = 0; j < GD; ++j)
          if (j < g) stale = stale || (app[j] == cv0) || (app[j] == cv1);
        if (stale) {
          asm volatile("s_waitcnt vmcnt(0)" ::: "memory");
          __builtin_amdgcn_sched_barrier(0);
          ga[g] = (unsigned)nbr[cv0 * CAP + lane];
          gb[g] = (unsigned)nbr[cv1 * CAP + lane];
        }
        int L0 = rln[cv0], L1 = rln[cv1];
        unsigned rawA = ga[g], rawB = gb[g];

        // resolve raw entries to live roots
        int rA = 0x7FFF, rB = 0x7FFF;
        if (lane < L0) rA = findroot(ren, (int)rawA);
        if (lane < L1) rB = findroot(ren, (int)rawB);

        // versioned marks: dedup (canonical lane via atomicMax) + membership
        ctr++;
        unsigned enc = (ctr << 6) + (unsigned)(63 - lane);
        bool wA = (lane < L0) && (rA != cv0);   // eff(v0) excludes self
        bool wB = (lane < L1) && (rB != cv1);   // eff(v1) excludes self
        if (wA) atomicMax(&markA[rA], enc);
        if (wB) atomicMax(&markB[rB], enc);
        asm volatile("s_waitcnt lgkmcnt(0)" ::: "memory");
        __builtin_amdgcn_sched_barrier(0);
        bool canonA = wA && (markA[rA] == enc);
        bool canonB = wB && (markB[rB] == enc);
        bool sh = canonA && ((markB[rA] >> 6) == ctr);   // rA in eff(v1)
        if (__popcll(__ballot(sh)) != 2) continue;

        // ---- commit merge cv1 -> cv0 ----
        if (L0 + L1 <= CAP) {
          // append raw(v1) to raw(v0); dedup deferred to future reads
          if (lane < L1) nbr[cv0 * CAP + L0 + lane] = (unsigned short)rawB;
          if (lane == 0) rln[cv0] = (unsigned short)(L0 + L1);
        } else {
          // compaction: write resolved deduped (effA ∪ effB) \ {cv0, cv1}
          bool pa = canonA && (rA != cv1);
          bool pb = canonB && (rB != cv0) && ((markA[rB] >> 6) != ctr);
          u64 ma = __ballot(pa);
          u64 mb = __ballot(pb);
          int na = __popcll(ma);
          int tot = na + __popcll(mb);
          if (tot > CAP) tot = CAP;
          if (pa) nbr[cv0 * CAP + __popcll(ma & below)] = (unsigned short)rA;
          if (pb) {
            int pos = na + __popcll(mb & below);
            if (pos < CAP) nbr[cv0 * CAP + pos] = (unsigned short)rB;
          }
          if (lane == 0) rln[cv0] = (unsigned short)tot;
        }
        if (lane == 0) {
          ren[cv1] = (unsigned short)cv0;
          events[nev] = make_int2(cv0, cv1);
        }
        asm volatile("s_waitcnt lgkmcnt(0)" ::: "memory");
        __builtin_amdgcn_sched_barrier(0);
        app[g] = cv0;
        nev++;
        count--;
        if (count <= target) stop = true;
      }
    }
  }
  if (lane == 0) nev_out[0] = nev;
}

// ---------------- reverse-replay: owner + weight per original vertex -------
__global__ void __launch_bounds__(256)
k_weights(const int2* __restrict__ events, const int* __restrict__ nev_p,
          int V, int* __restrict__ own, float* __restrict__ wgt) {
  __shared__ int O[MAXV];
  __shared__ unsigned short H[MAXV];
  __shared__ int2 evb[256];
  int tid = threadIdx.x;
  if (V > MAXV) return;
  for (int v = tid; v < V; v += blockDim.x) { O[v] = v; H[v] = 0; }
  int n = nev_p[0];
  __syncthreads();
  int nb = (n + 255) >> 8;
  for (int b = nb - 1; b >= 0; --b) {
    int bbase = b << 8;
    int cnt = n - bbase; if (cnt > 256) cnt = 256;
    if (tid < cnt) evb[tid] = events[bbase + tid];
    __syncthreads();
    if (tid == 0) {
      for (int k = cnt - 1; k >= 0; --k) {
        int2 ev = evb[k];
        int h = (int)H[ev.x] + 1;
        H[ev.x] = (unsigned short)h;
        H[ev.y] = (unsigned short)h;
        O[ev.y] = O[ev.x];
      }
    }
    __syncthreads();
  }
  for (int v = tid; v < V; v += blockDim.x) {
    own[v] = O[v];
    wgt[v] = ldexpf(1.0f, -(int)H[v]);
  }
}

// ---------------- output ---------------------------------------------------
__global__ void k_zero(float4* __restrict__ out, int n4) {
  int i = blockIdx.x * blockDim.x + threadIdx.x;
  if (i < n4) out[i] = make_float4(0.f, 0.f, 0.f, 0.f);
}

__global__ void k_scatter(const float* __restrict__ img, const int* __restrict__ own,
                          const float* __restrict__ wgt, float* __restrict__ out, int V) {
  int v = blockIdx.x;
  if (v >= V) return;
  float w = wgt[v];
  int o = own[v];
  const float* src = img + (size_t)v * F_DIM;
  float* dst = out + (size_t)o * F_DIM;
  if (w == 1.0f) {
    for (int f = threadIdx.x; f < F_DIM; f += blockDim.x) dst[f] = src[f];
  } else {
    for (int f = threadIdx.x; f < F_DIM; f += blockDim.x) atomicAdd(&dst[f], w * src[f]);
  }
}

extern "C" void kernel_launch(void* const* d_in, const int* in_sizes, int n_in,
                              void* d_out, int out_size, void* d_ws, size_t ws_size,
                              hipStream_t stream) {
  const float* img  = (const float*)d_in[0];
  const int* edges  = (const int*)d_in[1];
  const float* vs   = (const float*)d_in[2];
  int V = in_sizes[2] / 2;
  int E = in_sizes[1] / 2;
  int P = 1; while (P < E) P <<= 1;

  char* wsp = (char*)d_ws;
  size_t off = 0;
  auto alloc = [&](size_t bytes) -> void* {
    void* p = (void*)(wsp + off);
    off = (off + bytes + 255) & ~(size_t)255;
    return p;
  };
  double* sqd          = (double*)alloc((size_t)V * 8);
  u64* keys            = (u64*)alloc((size_t)P * 8);
  int* deg             = (int*)alloc((size_t)V * 4);
  unsigned short* nbr  = (unsigned short*)alloc((size_t)V * CAP * 2 + 256);
  unsigned char* elig  = (unsigned char*)alloc((size_t)E);
  unsigned* packed     = (unsigned*)alloc((size_t)E * 4);
  int2* events         = (int2*)alloc((size_t)(V / 2 + 64) * 8);
  int* nev             = (int*)alloc(256);
  int* own             = (int*)alloc((size_t)V * 4);
  float* wgt           = (float*)alloc((size_t)V * 4);

  hipLaunchKernelGGL(k_sq, dim3(V), dim3(64), 0, stream, img, sqd, V);
  int mx = V > E ? V : E;
  hipLaunchKernelGGL(k_prep, dim3((mx + 255) / 256), dim3(256), 0, stream, vs, edges, V, E, deg, elig);
  hipLaunchKernelGGL(k_lists, dim3((E + 255) / 256), dim3(256), 0, stream, edges, E, deg, nbr);
  hipLaunchKernelGGL(k_keys, dim3((P + 255) / 256), dim3(256), 0, stream, sqd, edges, E, P, keys);
  hipLaunchKernelGGL(k_sort, dim3(1), dim3(1024), 0, stream, keys, P);
  hipLaunchKernelGGL(k_reorder, dim3((E + 255) / 256), dim3(256), 0, stream, keys, edges, elig, E, packed);
  hipLaunchKernelGGL(k_decimate, dim3(1), dim3(64), 0, stream,
                     E, V, V / 2, packed, deg, nbr, events, nev);
  hipLaunchKernelGGL(k_weights, dim3(1), dim3(256), 0, stream, events, nev, V, own, wgt);
  int n4 = (V * F_DIM) / 4;
  hipLaunchKernelGGL(k_zero, dim3((n4 + 255) / 256), dim3(256), 0, stream, (float4*)d_out, n4);
  hipLaunchKernelGGL(k_scatter, dim3(V), dim3(256), 0, stream, img, own, wgt, (float*)d_out, V);
}